// Round 3
// baseline (428.808 us; speedup 1.0000x reference)
//
#include <hip/hip_runtime.h>

#define NB 2048
#define S_ 200
#define C_ 25
#define H_ 8
#define CP 28  // padded row stride (floats), 112 B = 16B-aligned rows

struct Row25 { float v[25]; };

__device__ __forceinline__ Row25 ldrow(const float* __restrict__ p) {
    Row25 r;
    const float4* p4 = (const float4*)p;
#pragma unroll
    for (int i = 0; i < 6; ++i) {
        float4 q = p4[i];
        r.v[4*i+0] = q.x; r.v[4*i+1] = q.y; r.v[4*i+2] = q.z; r.v[4*i+3] = q.w;
    }
    r.v[24] = p[24];
    return r;
}

// Opaque pin: forces elements into live VGPRs at this point; prevents
// rematerialization-from-LDS inside later loops.
__device__ __forceinline__ void pin(Row25& r) {
#pragma unroll
    for (int i = 0; i < 25; ++i) asm volatile("" : "+v"(r.v[i]));
}

__device__ __forceinline__ float dot25(const Row25& a, const Row25& b) {
    float s0 = 0.f, s1 = 0.f, s2 = 0.f, s3 = 0.f;
#pragma unroll
    for (int i = 0; i < 24; i += 4) {
        s0 = fmaf(a.v[i+0], b.v[i+0], s0);
        s1 = fmaf(a.v[i+1], b.v[i+1], s1);
        s2 = fmaf(a.v[i+2], b.v[i+2], s2);
        s3 = fmaf(a.v[i+3], b.v[i+3], s3);
    }
    s0 = fmaf(a.v[24], b.v[24], s0);
    return (s0 + s1) + (s2 + s3);
}

__global__ __launch_bounds__(256, 3) void ssm_syn_delay_kernel(
    const float* __restrict__ x,       const float* __restrict__ delay_W,
    const float* __restrict__ delay_b, const float* __restrict__ U_W,
    const float* __restrict__ U_b,     const float* __restrict__ A_W,
    const float* __restrict__ B_W,     const float* __restrict__ B_b,
    const float* __restrict__ out_W,   const float* __restrict__ out_b,
    float* __restrict__ out)
{
    // 52,800 B total -> 3 blocks/CU
    __shared__ float xs[S_ * CP];    // 22400: x[b] rows, padded
    __shared__ float dw[S_ * CP];    // 22400: delay_W rows, padded
    __shared__ float dbs[S_];        // 800
    __shared__ float lden[S_];       // 800: log(denom) per source timestep t
    __shared__ float p_s[S_ * H_];   // 6400: bgate*u, overwritten by h in phase 3

    const int tid = threadIdx.x;
    const int b   = blockIdx.x;
    const float* xb = x + (size_t)b * (S_ * C_);

    // ---- Phase 0: stage x[b] and delay_W into LDS (coalesced) ----
    for (int i = tid; i < S_ * C_; i += 256) {
        int r = i / C_, c = i - r * C_;
        xs[r * CP + c] = xb[i];
        dw[r * CP + c] = delay_W[i];
    }
    for (int i = tid; i < S_; i += 256) dbs[i] = delay_b[i];
    __syncthreads();

    // ---- Phase 1: log softmax denominators. Thread t owns source row t,
    //      scans all s. One distinct LDS row per iter (wave broadcast). ----
    {
        const int t  = tid;
        const int tc = (t < S_) ? t : (S_ - 1);
        Row25 xr = ldrow(&xs[tc * CP]);
        pin(xr);
        float d = 0.f;
        for (int s = 0; s < S_; ++s) {
            Row25 wr = ldrow(&dw[s * CP]);   // broadcast: 1 address/wave
            d += __expf(dbs[s] + dot25(xr, wr));
        }
        if (t < S_) lden[t] = __logf(d);
    }
    __syncthreads();

    // ---- Phase 2: x_del row s + u / bgate (recompute logits). Thread s
    //      owns output timestep s, scans all t. ----
    {
        const int s  = tid;
        const int sc = (s < S_) ? s : (S_ - 1);
        Row25 w = ldrow(&dw[sc * CP]);
        pin(w);                               // ~90 live VGPRs total: no AGPR spill
        const float bias = dbs[sc];
        Row25 acc;
#pragma unroll
        for (int i = 0; i < 25; ++i) acc.v[i] = 0.f;

        for (int t = 0; t < S_; ++t) {
            Row25 xr = ldrow(&xs[t * CP]);   // broadcast: 1 address/wave
            float e = __expf(bias + dot25(xr, w) - lden[t]);
#pragma unroll
            for (int i = 0; i < 25; ++i)
                acc.v[i] = fmaf(e, xr.v[i], acc.v[i]);
        }

        if (s < S_) {
#pragma unroll
            for (int h = 0; h < H_; ++h) {
                // wave-uniform weight rows from global -> scalar loads
                float uu = U_b[h];
                float bb = B_b[h];
#pragma unroll
                for (int i = 0; i < 25; ++i) {
                    uu = fmaf(acc.v[i], U_W[h * C_ + i], uu);
                    bb = fmaf(acc.v[i], B_W[h * C_ + i], bb);
                }
                float sg_ = 1.0f / (1.0f + __expf(-bb));
                p_s[s * H_ + h] = uu * sg_;
            }
        }
    }
    __syncthreads();

    // ---- Phase 3: linear recurrence h_s = A h_{s-1} + p_s (8 lanes) ----
    if (tid < H_) {
        const int i = tid;
        float Ar[H_];
#pragma unroll
        for (int j = 0; j < H_; ++j) Ar[j] = A_W[i * H_ + j];
        float h = 0.f;
        for (int s = 0; s < S_; ++s) {
            float acc = p_s[s * H_ + i];
#pragma unroll
            for (int j = 0; j < H_; ++j)
                acc = fmaf(Ar[j], __shfl(h, j, 8), acc);
            h = acc;
            p_s[s * H_ + i] = h;   // overwrite in place (hs)
        }
    }
    __syncthreads();

    // ---- Phase 4: out[b,s,c] = hs[s]·out_W[c,:] + out_b[c] ----
    float* ob_ptr = out + (size_t)b * (S_ * C_);
    for (int i = tid; i < S_ * C_; i += 256) {
        int s = i / C_, c = i - s * C_;
        float v = out_b[c];
#pragma unroll
        for (int h = 0; h < H_; ++h)
            v = fmaf(p_s[s * H_ + h], out_W[c * H_ + h], v);
        ob_ptr[i] = v;
    }
}

extern "C" void kernel_launch(void* const* d_in, const int* in_sizes, int n_in,
                              void* d_out, int out_size, void* d_ws, size_t ws_size,
                              hipStream_t stream) {
    const float* x       = (const float*)d_in[0];
    const float* delay_W = (const float*)d_in[1];
    const float* delay_b = (const float*)d_in[2];
    const float* U_W     = (const float*)d_in[3];
    const float* U_b     = (const float*)d_in[4];
    const float* A_W     = (const float*)d_in[5];
    const float* B_W     = (const float*)d_in[6];
    const float* B_b     = (const float*)d_in[7];
    const float* out_W   = (const float*)d_in[8];
    const float* out_b   = (const float*)d_in[9];
    float* out = (float*)d_out;

    ssm_syn_delay_kernel<<<NB, 256, 0, stream>>>(
        x, delay_W, delay_b, U_W, U_b, A_W, B_W, B_b, out_W, out_b, out);
}

// Round 4
// 376.377 us; speedup vs baseline: 1.1393x; 1.1393x over previous
//
#include <hip/hip_runtime.h>

#define NB 2048
#define S_ 200
#define C_ 25
#define H_ 8
#define CP 28  // padded row stride (floats), 112 B = 16B-aligned rows

struct Row25 { float v[25]; };

__device__ __forceinline__ Row25 ldrow(const float* __restrict__ p) {
    Row25 r;
    const float4* p4 = (const float4*)p;
#pragma unroll
    for (int i = 0; i < 6; ++i) {
        float4 q = p4[i];
        r.v[4*i+0] = q.x; r.v[4*i+1] = q.y; r.v[4*i+2] = q.z; r.v[4*i+3] = q.w;
    }
    r.v[24] = p[24];
    return r;
}

// Load a 25-float row with plain scalar indexing (for global, possibly
// unaligned-by-row pointers).
__device__ __forceinline__ Row25 ldrow_g(const float* __restrict__ p) {
    Row25 r;
#pragma unroll
    for (int i = 0; i < 25; ++i) r.v[i] = p[i];
    return r;
}

// Opaque pin: forces elements into live VGPRs; blocks remat-from-memory.
__device__ __forceinline__ void pin(Row25& r) {
#pragma unroll
    for (int i = 0; i < 25; ++i) asm volatile("" : "+v"(r.v[i]));
}

__device__ __forceinline__ float dot25(const Row25& a, const Row25& b) {
    float s0 = 0.f, s1 = 0.f, s2 = 0.f, s3 = 0.f;
#pragma unroll
    for (int i = 0; i < 24; i += 4) {
        s0 = fmaf(a.v[i+0], b.v[i+0], s0);
        s1 = fmaf(a.v[i+1], b.v[i+1], s1);
        s2 = fmaf(a.v[i+2], b.v[i+2], s2);
        s3 = fmaf(a.v[i+3], b.v[i+3], s3);
    }
    s0 = fmaf(a.v[24], b.v[24], s0);
    return (s0 + s1) + (s2 + s3);
}

// dot against a wave-uniform global row -> compiler emits s_loads (SMEM),
// FMAs take the weight as the single SGPR operand. No LDS, no extra VALU.
__device__ __forceinline__ float dot25g(const Row25& a, const float* __restrict__ w) {
    float s0 = 0.f, s1 = 0.f, s2 = 0.f, s3 = 0.f;
#pragma unroll
    for (int i = 0; i < 24; i += 4) {
        s0 = fmaf(a.v[i+0], w[i+0], s0);
        s1 = fmaf(a.v[i+1], w[i+1], s1);
        s2 = fmaf(a.v[i+2], w[i+2], s2);
        s3 = fmaf(a.v[i+3], w[i+3], s3);
    }
    s0 = fmaf(a.v[24], w[24], s0);
    return (s0 + s1) + (s2 + s3);
}

__global__ __launch_bounds__(256, 4) void ssm_syn_delay_kernel(
    const float* __restrict__ x,       const float* __restrict__ delay_W,
    const float* __restrict__ delay_b, const float* __restrict__ U_W,
    const float* __restrict__ U_b,     const float* __restrict__ A_W,
    const float* __restrict__ B_W,     const float* __restrict__ B_b,
    const float* __restrict__ out_W,   const float* __restrict__ out_b,
    float* __restrict__ out)
{
    // 29,600 B total -> 4 blocks/CU (VGPR-capped), grid = exactly 2 rounds
    __shared__ float xs[S_ * CP];    // 22400: x[b] rows, padded
    __shared__ float lden[S_];       //   800: log(denom) per source timestep t
    __shared__ float p_s[S_ * H_];   //  6400: bgate*u, overwritten by h later

    const int tid = threadIdx.x;
    const int b   = blockIdx.x;
    const float* xb = x + (size_t)b * (S_ * C_);

    // ---- Phase 0: stage x[b] into LDS (coalesced). delay_W stays global. ----
    for (int i = tid; i < S_ * C_; i += 256) {
        int r = i / C_, c = i - r * C_;
        xs[r * CP + c] = xb[i];
    }
    __syncthreads();

    // ---- Phase 1: log softmax denominators. Thread t owns source row t
    //      (resident in VGPRs); scans s with delay_W row via SCALAR loads. ----
    {
        const int t  = tid;
        const int tc = (t < S_) ? t : (S_ - 1);
        Row25 xr = ldrow(&xs[tc * CP]);
        pin(xr);
        float d = 0.f;
#pragma unroll 2
        for (int s = 0; s < S_; ++s) {
            const float* wr = delay_W + s * C_;   // wave-uniform -> s_load
            float bias = delay_b[s];              // wave-uniform -> s_load
            d += __expf(bias + dot25g(xr, wr));
        }
        if (t < S_) lden[t] = __logf(d);
    }
    __syncthreads();

    // ---- Phase 2: x_del row s + u / bgate (recompute logits). Thread s
    //      owns output row s; w resident in VGPRs; broadcasts xs rows. ----
    {
        const int s  = tid;
        const int sc = (s < S_) ? s : (S_ - 1);
        Row25 w = ldrow_g(delay_W + sc * C_);     // per-lane, once, L1/L2-hot
        pin(w);
        const float bias = delay_b[sc];           // per-lane, once
        Row25 acc;
#pragma unroll
        for (int i = 0; i < 25; ++i) acc.v[i] = 0.f;

#pragma unroll 2
        for (int t = 0; t < S_; ++t) {
            Row25 xr = ldrow(&xs[t * CP]);        // broadcast: 1 address/wave
            float e = __expf(bias + dot25(xr, w) - lden[t]);
#pragma unroll
            for (int i = 0; i < 25; ++i)
                acc.v[i] = fmaf(e, xr.v[i], acc.v[i]);
        }

        if (s < S_) {
#pragma unroll
            for (int h = 0; h < H_; ++h) {
                float uu = U_b[h];                // uniform -> s_load
                float bb = B_b[h];
#pragma unroll
                for (int i = 0; i < 25; ++i) {
                    uu = fmaf(acc.v[i], U_W[h * C_ + i], uu);
                    bb = fmaf(acc.v[i], B_W[h * C_ + i], bb);
                }
                float sg_ = 1.0f / (1.0f + __expf(-bb));
                p_s[s * H_ + h] = uu * sg_;
            }
        }
    }
    __syncthreads();

    // ---- Phase 3: linear recurrence h_s = A h_{s-1} + p_s (8 lanes) ----
    if (tid < H_) {
        const int i = tid;
        float Ar[H_];
#pragma unroll
        for (int j = 0; j < H_; ++j) Ar[j] = A_W[i * H_ + j];
        float h = 0.f;
        for (int s = 0; s < S_; ++s) {
            float acc = p_s[s * H_ + i];
#pragma unroll
            for (int j = 0; j < H_; ++j)
                acc = fmaf(Ar[j], __shfl(h, j, 8), acc);
            h = acc;
            p_s[s * H_ + i] = h;   // overwrite in place (hs)
        }
    }
    __syncthreads();

    // ---- Phase 4: out[b,s,c] = hs[s]·out_W[c,:] + out_b[c] ----
    float* ob_ptr = out + (size_t)b * (S_ * C_);
    for (int i = tid; i < S_ * C_; i += 256) {
        int s = i / C_, c = i - s * C_;
        float v = out_b[c];
#pragma unroll
        for (int h = 0; h < H_; ++h)
            v = fmaf(p_s[s * H_ + h], out_W[c * H_ + h], v);
        ob_ptr[i] = v;
    }
}

extern "C" void kernel_launch(void* const* d_in, const int* in_sizes, int n_in,
                              void* d_out, int out_size, void* d_ws, size_t ws_size,
                              hipStream_t stream) {
    const float* x       = (const float*)d_in[0];
    const float* delay_W = (const float*)d_in[1];
    const float* delay_b = (const float*)d_in[2];
    const float* U_W     = (const float*)d_in[3];
    const float* U_b     = (const float*)d_in[4];
    const float* A_W     = (const float*)d_in[5];
    const float* B_W     = (const float*)d_in[6];
    const float* B_b     = (const float*)d_in[7];
    const float* out_W   = (const float*)d_in[8];
    const float* out_b   = (const float*)d_in[9];
    float* out = (float*)d_out;

    ssm_syn_delay_kernel<<<NB, 256, 0, stream>>>(
        x, delay_W, delay_b, U_W, U_b, A_W, B_W, B_b, out_W, out_b, out);
}

// Round 5
// 301.311 us; speedup vs baseline: 1.4231x; 1.2491x over previous
//
#include <hip/hip_runtime.h>

#define NB 2048
#define S_ 200
#define C_ 25
#define H_ 8
#define WROWS 208        // padded row count for packed X / W arrays
#define STR 36           // dword stride of packed rows (multiple of 4 -> b128-aligned)
#define NSTRIP 13        // ceil(200/16) t-strips
#define NSTILE 13        // ceil(200/16) s-tiles
#define NPAIR 7          // ceil(13/2) strip pairs (K=32 each)
#define XDS 26           // x_del float stride in reused LDS

typedef __bf16   bf16x8 __attribute__((ext_vector_type(8)));
typedef float    f32x4  __attribute__((ext_vector_type(4)));
typedef unsigned uint4v __attribute__((ext_vector_type(4)));
typedef unsigned uint2v __attribute__((ext_vector_type(2)));

struct Frag { bf16x8 hi, lo; };

__device__ __forceinline__ unsigned short f2bf(float f) {
    unsigned u = __builtin_bit_cast(unsigned, f);
    return (unsigned short)((u + 0x7FFFu + ((u >> 16) & 1u)) >> 16);
}
__device__ __forceinline__ float bfh2f(unsigned short h) {
    return __builtin_bit_cast(float, (unsigned)h << 16);
}
// pack one f32 into (hi bf16 | lo bf16 << 16)
__device__ __forceinline__ unsigned pack_hl(float v) {
    unsigned short h = f2bf(v);
    unsigned short l = f2bf(v - bfh2f(h));
    return (unsigned)h | ((unsigned)l << 16);
}
__device__ __forceinline__ unsigned hi_pair(unsigned d0, unsigned d1) {
    return (d0 & 0xFFFFu) | (d1 << 16);
}
__device__ __forceinline__ unsigned lo_pair(unsigned d0, unsigned d1) {
    return (d0 >> 16) | (d1 & 0xFFFF0000u);
}
// build hi/lo bf16x8 frags from 8 packed dwords (elements j=0..7)
__device__ __forceinline__ Frag build_frag8(uint4v d0, uint4v d1) {
    uint4v h, l;
    h.x = hi_pair(d0.x, d0.y); h.y = hi_pair(d0.z, d0.w);
    h.z = hi_pair(d1.x, d1.y); h.w = hi_pair(d1.z, d1.w);
    l.x = lo_pair(d0.x, d0.y); l.y = lo_pair(d0.z, d0.w);
    l.z = lo_pair(d1.x, d1.y); l.w = lo_pair(d1.z, d1.w);
    Frag f;
    f.hi = __builtin_bit_cast(bf16x8, h);
    f.lo = __builtin_bit_cast(bf16x8, l);
    return f;
}
__device__ __forceinline__ f32x4 mfma16(bf16x8 a, bf16x8 b, f32x4 c) {
    return __builtin_amdgcn_mfma_f32_16x16x32_bf16(a, b, c, 0, 0, 0);
}
// split-precision D += A*B (drop lo*lo term)
__device__ __forceinline__ f32x4 mfma_split(const Frag& a, const Frag& b, f32x4 c) {
    c = mfma16(a.hi, b.hi, c);
    c = mfma16(a.hi, b.lo, c);
    c = mfma16(a.lo, b.hi, c);
    return c;
}

// ---------- prep kernel: pack delay_W (hi|lo bf16 dwords) into d_ws ----------
__global__ void prep_w_kernel(const float* __restrict__ delay_W, unsigned* __restrict__ W32g) {
    for (int i = threadIdx.x; i < WROWS * STR; i += 256) {
        int r = i / STR, c = i - r * STR;
        float v = (r < S_ && c < C_) ? delay_W[r * C_ + c] : 0.f;
        W32g[i] = pack_hl(v);
    }
}

// ---------- main kernel: one block per batch ----------
__global__ __launch_bounds__(256, 4) void ssm_syn_delay_kernel(
    const float* __restrict__ x,       const unsigned* __restrict__ W32g,
    const float* __restrict__ delay_b, const float* __restrict__ U_W,
    const float* __restrict__ U_b,     const float* __restrict__ A_W,
    const float* __restrict__ B_W,     const float* __restrict__ B_b,
    const float* __restrict__ out_W,   const float* __restrict__ out_b,
    float* __restrict__ out)
{
    // 39,808 B total -> 4 blocks/CU
    __shared__ __align__(16) unsigned X32[WROWS * STR]; // 29,952 B: packed x rows; later aliased by x_del + p_s
    __shared__ __align__(16) unsigned PB[4 * 512];      //  8,192 B: per-wave P transpose buffer (hi 256 dw, lo 256 dw)
    __shared__ float lsed[WROWS];                       //    832 B
    __shared__ float dbs_l[WROWS];                      //    832 B

    const int tid  = threadIdx.x;
    const int wid  = tid >> 6;
    const int lane = tid & 63;
    const int q    = lane >> 4;     // quad 0..3
    const int n    = lane & 15;     // col-lane 0..15
    const int b    = blockIdx.x;
    const float* xb = x + (size_t)b * (S_ * C_);

    // ---- Phase 0: stage packed x rows + delay_b into LDS ----
    for (int i = tid; i < WROWS * STR; i += 256) {
        int r = i / STR, c = i - r * STR;
        float v = (r < S_ && c < C_) ? xb[r * C_ + c] : 0.f;
        X32[i] = pack_hl(v);
    }
    for (int i = tid; i < WROWS; i += 256) dbs_l[i] = (i < S_) ? delay_b[i] : 0.f;
    __syncthreads();

    // ---- Pass 1: lse[t] via MFMA. Wave owns t-strips wid, wid+4, ... ----
    for (int st = wid; st < NSTRIP; st += 4) {
        // A-frag: A[m=t][k=c], lane: m=n, k=q*8+j
        const int t = st * 16 + n;
        const uint4v* xp = (const uint4v*)&X32[t * STR + q * 8];
        Frag fa = build_frag8(xp[0], xp[1]);
        float rs0 = 0.f, rs1 = 0.f, rs2 = 0.f, rs3 = 0.f;
        for (int sv = 0; sv < NSTILE; ++sv) {
            const int s = sv * 16 + n;
            const uint4v* wp = (const uint4v*)&W32g[s * STR + q * 8];
            Frag fb = build_frag8(wp[0], wp[1]);   // B[k=c][n=s]
            f32x4 L = {0.f, 0.f, 0.f, 0.f};
            L = mfma_split(fa, fb, L);
            const float dbv = dbs_l[s];
            const bool valid = (s < S_);
            float e0 = __expf(L[0] + dbv); rs0 += valid ? e0 : 0.f;
            float e1 = __expf(L[1] + dbv); rs1 += valid ? e1 : 0.f;
            float e2 = __expf(L[2] + dbv); rs2 += valid ? e2 : 0.f;
            float e3 = __expf(L[3] + dbv); rs3 += valid ? e3 : 0.f;
        }
        // reduce across the 16 col-lanes of each quad
#pragma unroll
        for (int off = 1; off < 16; off <<= 1) {
            rs0 += __shfl_xor(rs0, off);
            rs1 += __shfl_xor(rs1, off);
            rs2 += __shfl_xor(rs2, off);
            rs3 += __shfl_xor(rs3, off);
        }
        if (n < 4) {
            float v = (n == 0) ? rs0 : (n == 1) ? rs1 : (n == 2) ? rs2 : rs3;
            lsed[st * 16 + q * 4 + n] = __logf(v);
        }
    }
    __syncthreads();

    // ---- Pass 2: x_del = P^T X via MFMA, flash-style over strip pairs ----
    f32x4 acc[4][2];
#pragma unroll
    for (int i = 0; i < 4; ++i)
#pragma unroll
        for (int j = 0; j < 2; ++j) acc[i][j] = f32x4{0.f, 0.f, 0.f, 0.f};

    const int pb_hi = wid * 512;        // per-wave PB regions
    const int pb_lo = wid * 512 + 256;

    for (int pair = 0; pair < NPAIR; ++pair) {
        const int sA = 2 * pair, sB = sA + 1;
        const bool bval = (sB < NSTRIP);
        // A1 frags for both strips
        const uint4v* xpA = (const uint4v*)&X32[(sA * 16 + n) * STR + q * 8];
        Frag faA = build_frag8(xpA[0], xpA[1]);
        Frag faB;
        if (bval) {
            const uint4v* xpB = (const uint4v*)&X32[(sB * 16 + n) * STR + q * 8];
            faB = build_frag8(xpB[0], xpB[1]);
        }
        f32x4 lseA = *(const f32x4*)&lsed[sA * 16 + q * 4];
        f32x4 lseB = bval ? *(const f32x4*)&lsed[sB * 16 + q * 4] : f32x4{0,0,0,0};
        // B2 frags: B[k=t][n=c] for both c-tiles, t = pair*32 + q*8 + j
        Frag b2[2];
#pragma unroll
        for (int ct = 0; ct < 2; ++ct) {
            const int c = ct * 16 + n;
            uint4v d0, d1;
#pragma unroll
            for (int j = 0; j < 4; ++j) {
                int t = pair * 32 + q * 8 + j;
                ((unsigned*)&d0)[j] = (t < WROWS) ? X32[t * STR + c] : 0u;
            }
#pragma unroll
            for (int j = 0; j < 4; ++j) {
                int t = pair * 32 + q * 8 + 4 + j;
                ((unsigned*)&d1)[j] = (t < WROWS) ? X32[t * STR + c] : 0u;
            }
            b2[ct] = build_frag8(d0, d1);
        }

        int si = 0;
        for (int sv = wid; sv < NSTILE; sv += 4, ++si) {
            const int s = sv * 16 + n;
            const uint4v* wp = (const uint4v*)&W32g[s * STR + q * 8];
            Frag fb = build_frag8(wp[0], wp[1]);
            const float dbv = dbs_l[s];
            // strip A logits -> P -> PB (k = 4q+r, dwords 2q..2q+1)
            {
                f32x4 L = {0.f, 0.f, 0.f, 0.f};
                L = mfma_split(faA, fb, L);
                float e0 = __expf(L[0] + dbv - lseA[0]);
                float e1 = __expf(L[1] + dbv - lseA[1]);
                float e2 = __expf(L[2] + dbv - lseA[2]);
                float e3 = __expf(L[3] + dbv - lseA[3]);
                unsigned short h0 = f2bf(e0), h1 = f2bf(e1), h2 = f2bf(e2), h3 = f2bf(e3);
                uint2v hv, lv;
                hv.x = (unsigned)h0 | ((unsigned)h1 << 16);
                hv.y = (unsigned)h2 | ((unsigned)h3 << 16);
                lv.x = (unsigned)f2bf(e0 - bfh2f(h0)) | ((unsigned)f2bf(e1 - bfh2f(h1)) << 16);
                lv.y = (unsigned)f2bf(e2 - bfh2f(h2)) | ((unsigned)f2bf(e3 - bfh2f(h3)) << 16);
                *(uint2v*)&PB[pb_hi + n * 16 + 2 * q] = hv;
                *(uint2v*)&PB[pb_lo + n * 16 + 2 * q] = lv;
            }
            // strip B (or zeros)
            {
                uint2v hv = {0u, 0u}, lv = {0u, 0u};
                if (bval) {
                    f32x4 L = {0.f, 0.f, 0.f, 0.f};
                    L = mfma_split(faB, fb, L);
                    float e0 = __expf(L[0] + dbv - lseB[0]);
                    float e1 = __expf(L[1] + dbv - lseB[1]);
                    float e2 = __expf(L[2] + dbv - lseB[2]);
                    float e3 = __expf(L[3] + dbv - lseB[3]);
                    unsigned short h0 = f2bf(e0), h1 = f2bf(e1), h2 = f2bf(e2), h3 = f2bf(e3);
                    hv.x = (unsigned)h0 | ((unsigned)h1 << 16);
                    hv.y = (unsigned)h2 | ((unsigned)h3 << 16);
                    lv.x = (unsigned)f2bf(e0 - bfh2f(h0)) | ((unsigned)f2bf(e1 - bfh2f(h1)) << 16);
                    lv.y = (unsigned)f2bf(e2 - bfh2f(h2)) | ((unsigned)f2bf(e3 - bfh2f(h3)) << 16);
                }
                *(uint2v*)&PB[pb_hi + n * 16 + 8 + 2 * q] = hv;
                *(uint2v*)&PB[pb_lo + n * 16 + 8 + 2 * q] = lv;
            }
            // read back in A-layout: A[m=s][k=t], lane: m=n, k=q*8+j
            uint4v ha = *(const uint4v*)&PB[pb_hi + n * 16 + 4 * q];
            uint4v la = *(const uint4v*)&PB[pb_lo + n * 16 + 4 * q];
            bf16x8 a2h = __builtin_bit_cast(bf16x8, ha);
            bf16x8 a2l = __builtin_bit_cast(bf16x8, la);
#pragma unroll
            for (int ct = 0; ct < 2; ++ct) {
                f32x4 c4 = acc[si][ct];
                c4 = mfma16(a2h, b2[ct].hi, c4);
                c4 = mfma16(a2l, b2[ct].hi, c4);
                c4 = mfma16(a2h, b2[ct].lo, c4);
                acc[si][ct] = c4;
            }
        }
    }
    __syncthreads();   // all X32 reads done; safe to alias

    // ---- store x_del into reused LDS (float, stride XDS) ----
    float* xdelf = (float*)&X32[0];
    float* p_s   = (float*)&X32[5696];   // 200*8 floats, after x_del's 5200
    {
        int si = 0;
        for (int sv = wid; sv < NSTILE; sv += 4, ++si) {
#pragma unroll
            for (int ct = 0; ct < 2; ++ct) {
                const int c = ct * 16 + n;
                if (c < C_) {
#pragma unroll
                    for (int r = 0; r < 4; ++r) {
                        const int s = sv * 16 + q * 4 + r;
                        if (s < S_) xdelf[s * XDS + c] = acc[si][ct][r];
                    }
                }
            }
        }
    }
    __syncthreads();

    // ---- u / bgate epilogue: thread s owns output timestep s ----
    if (tid < S_) {
        const int s = tid;
        float a[C_];
#pragma unroll
        for (int i = 0; i < C_; ++i) a[i] = xdelf[s * XDS + i];
#pragma unroll
        for (int h = 0; h < H_; ++h) {
            float uu = U_b[h];
            float bb = B_b[h];
#pragma unroll
            for (int i = 0; i < C_; ++i) {
                uu = fmaf(a[i], U_W[h * C_ + i], uu);
                bb = fmaf(a[i], B_W[h * C_ + i], bb);
            }
            float sg_ = 1.0f / (1.0f + __expf(-bb));
            p_s[s * H_ + h] = uu * sg_;
        }
    }
    __syncthreads();

    // ---- linear recurrence h_s = A h_{s-1} + p_s (8 lanes) ----
    if (tid < H_) {
        const int i = tid;
        float Ar[H_];
#pragma unroll
        for (int j = 0; j < H_; ++j) Ar[j] = A_W[i * H_ + j];
        float h = 0.f;
        for (int s = 0; s < S_; ++s) {
            float a2 = p_s[s * H_ + i];
#pragma unroll
            for (int j = 0; j < H_; ++j)
                a2 = fmaf(Ar[j], __shfl(h, j, 8), a2);
            h = a2;
            p_s[s * H_ + i] = h;
        }
    }
    __syncthreads();

    // ---- out[b,s,c] = hs[s]·out_W[c,:] + out_b[c] ----
    float* ob_ptr = out + (size_t)b * (S_ * C_);
    for (int i = tid; i < S_ * C_; i += 256) {
        int s = i / C_, c = i - s * C_;
        float v = out_b[c];
#pragma unroll
        for (int h = 0; h < H_; ++h)
            v = fmaf(p_s[s * H_ + h], out_W[c * H_ + h], v);
        ob_ptr[i] = v;
    }
}

extern "C" void kernel_launch(void* const* d_in, const int* in_sizes, int n_in,
                              void* d_out, int out_size, void* d_ws, size_t ws_size,
                              hipStream_t stream) {
    const float* x       = (const float*)d_in[0];
    const float* delay_W = (const float*)d_in[1];
    const float* delay_b = (const float*)d_in[2];
    const float* U_W     = (const float*)d_in[3];
    const float* U_b     = (const float*)d_in[4];
    const float* A_W     = (const float*)d_in[5];
    const float* B_W     = (const float*)d_in[6];
    const float* B_b     = (const float*)d_in[7];
    const float* out_W   = (const float*)d_in[8];
    const float* out_b   = (const float*)d_in[9];
    float* out = (float*)d_out;
    unsigned* W32g = (unsigned*)d_ws;   // 208*36*4 = 29,952 B

    prep_w_kernel<<<1, 256, 0, stream>>>(delay_W, W32g);
    ssm_syn_delay_kernel<<<NB, 256, 0, stream>>>(
        x, W32g, delay_b, U_W, U_b, A_W, B_W, B_b, out_W, out_b, out);
}

// Round 6
// 283.822 us; speedup vs baseline: 1.5108x; 1.0616x over previous
//
#include <hip/hip_runtime.h>

#define NB 2048
#define S_ 200
#define C_ 25
#define H_ 8
#define WROWS 208        // padded row count for packed X / W arrays
#define STR 36           // dword stride of packed rows (multiple of 4 -> b128-aligned)
#define NSTRIP 13        // ceil(200/16) t-strips
#define NSTILE 13        // ceil(200/16) s-tiles
#define NPAIR 7          // ceil(13/2) strip pairs (K=32 each)
#define XDS 26           // x_del float stride in reused LDS

typedef __bf16   bf16x8 __attribute__((ext_vector_type(8)));
typedef float    f32x4  __attribute__((ext_vector_type(4)));
typedef unsigned uint4v __attribute__((ext_vector_type(4)));
typedef unsigned uint2v __attribute__((ext_vector_type(2)));

struct Frag { bf16x8 hi, lo; };

__device__ __forceinline__ unsigned short f2bf(float f) {
    unsigned u = __builtin_bit_cast(unsigned, f);
    return (unsigned short)((u + 0x7FFFu + ((u >> 16) & 1u)) >> 16);
}
__device__ __forceinline__ float bfh2f(unsigned short h) {
    return __builtin_bit_cast(float, (unsigned)h << 16);
}
// pack one f32 into (hi bf16 | lo bf16 << 16)
__device__ __forceinline__ unsigned pack_hl(float v) {
    unsigned short h = f2bf(v);
    unsigned short l = f2bf(v - bfh2f(h));
    return (unsigned)h | ((unsigned)l << 16);
}
__device__ __forceinline__ unsigned hi_pair(unsigned d0, unsigned d1) {
    return (d0 & 0xFFFFu) | (d1 << 16);
}
__device__ __forceinline__ unsigned lo_pair(unsigned d0, unsigned d1) {
    return (d0 >> 16) | (d1 & 0xFFFF0000u);
}
// build hi/lo bf16x8 frags from 8 packed dwords (elements j=0..7)
__device__ __forceinline__ Frag build_frag8(uint4v d0, uint4v d1) {
    uint4v h, l;
    h.x = hi_pair(d0.x, d0.y); h.y = hi_pair(d0.z, d0.w);
    h.z = hi_pair(d1.x, d1.y); h.w = hi_pair(d1.z, d1.w);
    l.x = lo_pair(d0.x, d0.y); l.y = lo_pair(d0.z, d0.w);
    l.z = lo_pair(d1.x, d1.y); l.w = lo_pair(d1.z, d1.w);
    Frag f;
    f.hi = __builtin_bit_cast(bf16x8, h);
    f.lo = __builtin_bit_cast(bf16x8, l);
    return f;
}
// hi-only variant (for the PV B operand; lo term dropped, see error budget)
__device__ __forceinline__ bf16x8 build_hi8(uint4v d0, uint4v d1) {
    uint4v h;
    h.x = hi_pair(d0.x, d0.y); h.y = hi_pair(d0.z, d0.w);
    h.z = hi_pair(d1.x, d1.y); h.w = hi_pair(d1.z, d1.w);
    return __builtin_bit_cast(bf16x8, h);
}
__device__ __forceinline__ f32x4 mfma16(bf16x8 a, bf16x8 b, f32x4 c) {
    return __builtin_amdgcn_mfma_f32_16x16x32_bf16(a, b, c, 0, 0, 0);
}
// split-precision D += A*B (drop lo*lo term)
__device__ __forceinline__ f32x4 mfma_split(const Frag& a, const Frag& b, f32x4 c) {
    c = mfma16(a.hi, b.hi, c);
    c = mfma16(a.hi, b.lo, c);
    c = mfma16(a.lo, b.hi, c);
    return c;
}

// ---------- prep kernel: pack delay_W (hi|lo bf16 dwords) into d_ws ----------
__global__ void prep_w_kernel(const float* __restrict__ delay_W, unsigned* __restrict__ W32g) {
    for (int i = blockIdx.x * 256 + threadIdx.x; i < WROWS * STR; i += 16 * 256) {
        int r = i / STR, c = i - r * STR;
        float v = (r < S_ && c < C_) ? delay_W[r * C_ + c] : 0.f;
        W32g[i] = pack_hl(v);
    }
}

// ---------- main kernel: one block per batch ----------
__global__ __launch_bounds__(256, 4) void ssm_syn_delay_kernel(
    const float* __restrict__ x,       const unsigned* __restrict__ W32g,
    const float* __restrict__ delay_b, const float* __restrict__ U_W,
    const float* __restrict__ U_b,     const float* __restrict__ A_W,
    const float* __restrict__ B_W,     const float* __restrict__ B_b,
    const float* __restrict__ out_W,   const float* __restrict__ out_b,
    float* __restrict__ out)
{
    // 39,808 B total -> 4 blocks/CU
    __shared__ __align__(16) unsigned X32[WROWS * STR]; // 29,952 B: packed x rows; later aliased by x_del + p_s
    __shared__ __align__(16) unsigned PB[4 * 512];      //  8,192 B: per-wave P transpose buffer (hi 256 dw, lo 256 dw)
    __shared__ float lsed[WROWS];                       //    832 B
    __shared__ float dbs_l[WROWS];                      //    832 B

    const int tid  = threadIdx.x;
    const int wid  = tid >> 6;
    const int lane = tid & 63;
    const int q    = lane >> 4;     // quad 0..3
    const int n    = lane & 15;     // col-lane 0..15
    const int b    = blockIdx.x;
    const float* xb = x + (size_t)b * (S_ * C_);

    // ---- Phase 0: stage packed x rows + delay_b into LDS ----
    for (int i = tid; i < WROWS * STR; i += 256) {
        int r = i / STR, c = i - r * STR;
        float v = (r < S_ && c < C_) ? xb[r * C_ + c] : 0.f;
        X32[i] = pack_hl(v);
    }
    for (int i = tid; i < WROWS; i += 256) dbs_l[i] = (i < S_) ? delay_b[i] : 0.f;
    __syncthreads();

    // ---- Pass 1: lse[t] via MFMA. Wave owns t-strips wid, wid+4, ... ----
    for (int st = wid; st < NSTRIP; st += 4) {
        // A-frag: A[m=t][k=c], lane: m=n, k=q*8+j
        const int t = st * 16 + n;
        const uint4v* xp = (const uint4v*)&X32[t * STR + q * 8];
        Frag fa = build_frag8(xp[0], xp[1]);
        float rs0 = 0.f, rs1 = 0.f, rs2 = 0.f, rs3 = 0.f;
        for (int sv = 0; sv < NSTILE; ++sv) {
            const int s = sv * 16 + n;
            const uint4v* wp = (const uint4v*)&W32g[s * STR + q * 8];
            Frag fb = build_frag8(wp[0], wp[1]);   // B[k=c][n=s]
            f32x4 L = {0.f, 0.f, 0.f, 0.f};
            L = mfma_split(fa, fb, L);
            const float dbv = dbs_l[s];
            const bool valid = (s < S_);
            float e0 = __expf(L[0] + dbv); rs0 += valid ? e0 : 0.f;
            float e1 = __expf(L[1] + dbv); rs1 += valid ? e1 : 0.f;
            float e2 = __expf(L[2] + dbv); rs2 += valid ? e2 : 0.f;
            float e3 = __expf(L[3] + dbv); rs3 += valid ? e3 : 0.f;
        }
        // reduce across the 16 col-lanes of each quad
#pragma unroll
        for (int off = 1; off < 16; off <<= 1) {
            rs0 += __shfl_xor(rs0, off);
            rs1 += __shfl_xor(rs1, off);
            rs2 += __shfl_xor(rs2, off);
            rs3 += __shfl_xor(rs3, off);
        }
        if (n < 4) {
            float v = (n == 0) ? rs0 : (n == 1) ? rs1 : (n == 2) ? rs2 : rs3;
            lsed[st * 16 + q * 4 + n] = __logf(v);
        }
    }
    __syncthreads();

    // ---- Pass 2: x_del = P^T X via MFMA, flash-style over strip pairs ----
    // acc indexed ONLY by compile-time constants -> stays in VGPRs (no scratch)
    f32x4 acc[4][2];
#pragma unroll
    for (int i = 0; i < 4; ++i)
#pragma unroll
        for (int j = 0; j < 2; ++j) acc[i][j] = f32x4{0.f, 0.f, 0.f, 0.f};

    const int pb_hi = wid * 512;        // per-wave PB regions
    const int pb_lo = wid * 512 + 256;

    for (int pair = 0; pair < NPAIR; ++pair) {
        const int sA = 2 * pair, sB = sA + 1;
        const bool bval = (sB < NSTRIP);
        // A1 frags for both strips
        const uint4v* xpA = (const uint4v*)&X32[(sA * 16 + n) * STR + q * 8];
        Frag faA = build_frag8(xpA[0], xpA[1]);
        Frag faB;
        if (bval) {
            const uint4v* xpB = (const uint4v*)&X32[(sB * 16 + n) * STR + q * 8];
            faB = build_frag8(xpB[0], xpB[1]);
        }
        f32x4 lseA = *(const f32x4*)&lsed[sA * 16 + q * 4];
        f32x4 lseB = bval ? *(const f32x4*)&lsed[sB * 16 + q * 4] : f32x4{0,0,0,0};
        // B2 frags (hi only): B[k=t][n=c] for both c-tiles, t = pair*32 + q*8 + j
        bf16x8 b2h[2];
#pragma unroll
        for (int ct = 0; ct < 2; ++ct) {
            const int c = ct * 16 + n;
            uint4v d0, d1;
#pragma unroll
            for (int j = 0; j < 4; ++j) {
                int t = pair * 32 + q * 8 + j;
                ((unsigned*)&d0)[j] = (t < WROWS) ? X32[t * STR + c] : 0u;
            }
#pragma unroll
            for (int j = 0; j < 4; ++j) {
                int t = pair * 32 + q * 8 + 4 + j;
                ((unsigned*)&d1)[j] = (t < WROWS) ? X32[t * STR + c] : 0u;
            }
            b2h[ct] = build_hi8(d0, d1);
        }

#pragma unroll
        for (int si = 0; si < 4; ++si) {
            const int sv = wid + 4 * si;
            if (sv >= NSTILE) continue;          // wave-uniform branch
            const int s = sv * 16 + n;
            const uint4v* wp = (const uint4v*)&W32g[s * STR + q * 8];
            Frag fb = build_frag8(wp[0], wp[1]);
            const float dbv = dbs_l[s];
            // strip A logits -> P -> PB (k = 4q+r, dwords 2q..2q+1)
            {
                f32x4 L = {0.f, 0.f, 0.f, 0.f};
                L = mfma_split(faA, fb, L);
                float e0 = __expf(L[0] + dbv - lseA[0]);
                float e1 = __expf(L[1] + dbv - lseA[1]);
                float e2 = __expf(L[2] + dbv - lseA[2]);
                float e3 = __expf(L[3] + dbv - lseA[3]);
                unsigned short h0 = f2bf(e0), h1 = f2bf(e1), h2 = f2bf(e2), h3 = f2bf(e3);
                uint2v hv, lv;
                hv.x = (unsigned)h0 | ((unsigned)h1 << 16);
                hv.y = (unsigned)h2 | ((unsigned)h3 << 16);
                lv.x = (unsigned)f2bf(e0 - bfh2f(h0)) | ((unsigned)f2bf(e1 - bfh2f(h1)) << 16);
                lv.y = (unsigned)f2bf(e2 - bfh2f(h2)) | ((unsigned)f2bf(e3 - bfh2f(h3)) << 16);
                *(uint2v*)&PB[pb_hi + n * 16 + 2 * q] = hv;
                *(uint2v*)&PB[pb_lo + n * 16 + 2 * q] = lv;
            }
            // strip B (or zeros)
            {
                uint2v hv = {0u, 0u}, lv = {0u, 0u};
                if (bval) {
                    f32x4 L = {0.f, 0.f, 0.f, 0.f};
                    L = mfma_split(faB, fb, L);
                    float e0 = __expf(L[0] + dbv - lseB[0]);
                    float e1 = __expf(L[1] + dbv - lseB[1]);
                    float e2 = __expf(L[2] + dbv - lseB[2]);
                    float e3 = __expf(L[3] + dbv - lseB[3]);
                    unsigned short h0 = f2bf(e0), h1 = f2bf(e1), h2 = f2bf(e2), h3 = f2bf(e3);
                    hv.x = (unsigned)h0 | ((unsigned)h1 << 16);
                    hv.y = (unsigned)h2 | ((unsigned)h3 << 16);
                    lv.x = (unsigned)f2bf(e0 - bfh2f(h0)) | ((unsigned)f2bf(e1 - bfh2f(h1)) << 16);
                    lv.y = (unsigned)f2bf(e2 - bfh2f(h2)) | ((unsigned)f2bf(e3 - bfh2f(h3)) << 16);
                }
                *(uint2v*)&PB[pb_hi + n * 16 + 8 + 2 * q] = hv;
                *(uint2v*)&PB[pb_lo + n * 16 + 8 + 2 * q] = lv;
            }
            // read back in A-layout: A[m=s][k=t], lane: m=n, k=q*8+j
            uint4v ha = *(const uint4v*)&PB[pb_hi + n * 16 + 4 * q];
            uint4v la = *(const uint4v*)&PB[pb_lo + n * 16 + 4 * q];
            bf16x8 a2h = __builtin_bit_cast(bf16x8, ha);
            bf16x8 a2l = __builtin_bit_cast(bf16x8, la);
#pragma unroll
            for (int ct = 0; ct < 2; ++ct) {
                f32x4 c4 = acc[si][ct];
                c4 = mfma16(a2h, b2h[ct], c4);
                c4 = mfma16(a2l, b2h[ct], c4);
                acc[si][ct] = c4;
            }
        }
    }
    __syncthreads();   // all X32 reads done; safe to alias

    // ---- store x_del into reused LDS (float, stride XDS) ----
    float* xdelf = (float*)&X32[0];
    float* p_s   = (float*)&X32[5696];   // 200*8 floats, after x_del's 5200
#pragma unroll
    for (int si = 0; si < 4; ++si) {
        const int sv = wid + 4 * si;
        if (sv >= NSTILE) continue;
#pragma unroll
        for (int ct = 0; ct < 2; ++ct) {
            const int c = ct * 16 + n;
            if (c < C_) {
#pragma unroll
                for (int r = 0; r < 4; ++r) {
                    const int s = sv * 16 + q * 4 + r;
                    if (s < S_) xdelf[s * XDS + c] = acc[si][ct][r];
                }
            }
        }
    }
    __syncthreads();

    // ---- u / bgate epilogue: thread s owns output timestep s ----
    if (tid < S_) {
        const int s = tid;
        float a[C_];
#pragma unroll
        for (int i = 0; i < C_; ++i) a[i] = xdelf[s * XDS + i];
#pragma unroll
        for (int h = 0; h < H_; ++h) {
            float uu = U_b[h];
            float bb = B_b[h];
#pragma unroll
            for (int i = 0; i < C_; ++i) {
                uu = fmaf(a[i], U_W[h * C_ + i], uu);
                bb = fmaf(a[i], B_W[h * C_ + i], bb);
            }
            float sg_ = 1.0f / (1.0f + __expf(-bb));
            p_s[s * H_ + h] = uu * sg_;
        }
    }
    __syncthreads();

    // ---- linear recurrence h_s = A h_{s-1} + p_s (8 lanes) ----
    if (tid < H_) {
        const int i = tid;
        float Ar[H_];
#pragma unroll
        for (int j = 0; j < H_; ++j) Ar[j] = A_W[i * H_ + j];
        float h = 0.f;
        for (int s = 0; s < S_; ++s) {
            float a2 = p_s[s * H_ + i];
#pragma unroll
            for (int j = 0; j < H_; ++j)
                a2 = fmaf(Ar[j], __shfl(h, j, 8), a2);
            h = a2;
            p_s[s * H_ + i] = h;
        }
    }
    __syncthreads();

    // ---- out[b,s,c] = hs[s]·out_W[c,:] + out_b[c] ----
    float* ob_ptr = out + (size_t)b * (S_ * C_);
    for (int i = tid; i < S_ * C_; i += 256) {
        int s = i / C_, c = i - s * C_;
        float v = out_b[c];
#pragma unroll
        for (int h = 0; h < H_; ++h)
            v = fmaf(p_s[s * H_ + h], out_W[c * H_ + h], v);
        ob_ptr[i] = v;
    }
}

extern "C" void kernel_launch(void* const* d_in, const int* in_sizes, int n_in,
                              void* d_out, int out_size, void* d_ws, size_t ws_size,
                              hipStream_t stream) {
    const float* x       = (const float*)d_in[0];
    const float* delay_W = (const float*)d_in[1];
    const float* delay_b = (const float*)d_in[2];
    const float* U_W     = (const float*)d_in[3];
    const float* U_b     = (const float*)d_in[4];
    const float* A_W     = (const float*)d_in[5];
    const float* B_W     = (const float*)d_in[6];
    const float* B_b     = (const float*)d_in[7];
    const float* out_W   = (const float*)d_in[8];
    const float* out_b   = (const float*)d_in[9];
    float* out = (float*)d_out;
    unsigned* W32g = (unsigned*)d_ws;   // 208*36*4 = 29,952 B

    prep_w_kernel<<<16, 256, 0, stream>>>(delay_W, W32g);
    ssm_syn_delay_kernel<<<NB, 256, 0, stream>>>(
        x, W32g, delay_b, U_W, U_b, A_W, B_W, B_b, out_W, out_b, out);
}